// Round 14
// baseline (125.952 us; speedup 1.0000x reference)
//
#include <hip/hip_runtime.h>
#include <hip/hip_bf16.h>

// TripletLoss N=8192, D=128. Round 15 (resubmit -- prior round hit GPU
// acquisition timeout): 32x32 MFMA, doubled block supply.
// Round-14 post-mortem: spill fixed (VGPR 80, WRITE 1.26MB, conflicts 0)
// but dur 63.5us at Occupancy 21% / VALU 28% -- pure latency-bound, block
// supply (1024 = 4/CU) below register-allowed residency (512/96 = 5
// waves/SIMD). Single change: JSPLIT 16 -> 32 (2048 blocks, jspan 256):
// scheduler keeps 5 waves/SIMD resident and backfills the corr-head
// imbalance. Partial = 2MB (launcher falls back to jsplit 16 if ws tight).
// t-units: Fb,x2 pre-scaled by AK1=sqrt2*log2(e); C-init -(x2i+x2j)/2 =>
// acc = -AK1^2*d2/2; t=sqrt(-acc); exp(-dist)=exp2(-t); dist=t*ln2;
// positives exp(dist-30)=exp2(t+C2).

typedef __bf16 bf16x8 __attribute__((ext_vector_type(8)));
typedef float f32x16 __attribute__((ext_vector_type(16)));

#define NROWS 8192
#define DIM 128
#define JTILE 64
#define LDS_STRIDE 136    // 128+8 bf16 pad: 272B rows (17x16B, odd -> spread)
#define NLABELS 512
#define GCAP 64           // max rows/label (E=16; P(>64) ~ 1e-30)
#define MARGIN_F 0.3f
#define AK1F 2.04027892f      // sqrt2 * log2(e)
#define AK1SQ 4.16273807f     // AK1^2
#define EPS_T 2.08137e-8f     // AK1^2 * 5e-9 (matches reference clip(d2,1e-8))
#define C2F (-43.2808512f)    // -30*log2(e)
#define LN2F 0.69314718f

// ---------------- kernel 1: scaled bf16 cast + row norms + zero gstat ------
__global__ __launch_bounds__(256) void prep_kernel(const float* __restrict__ F,
                                                   __hip_bfloat16* __restrict__ Fb,
                                                   float* __restrict__ x2,
                                                   float* __restrict__ gstat) {
    const int tid = threadIdx.x;
    const int wave = tid >> 6, lane = tid & 63;
    const int row = blockIdx.x * 4 + wave;
    float2 f = ((const float2*)(F + (size_t)row * DIM))[lane];
    f.x *= AK1F; f.y *= AK1F;
    ((__hip_bfloat162*)(Fb + (size_t)row * DIM))[lane] = __float22bfloat162_rn(f);
    float ss = f.x * f.x + f.y * f.y;
#pragma unroll
    for (int m = 32; m > 0; m >>= 1) ss += __shfl_xor(ss, m, 64);
    if (lane == 0) x2[row] = ss;
    if (blockIdx.x == 0 && tid < 4) gstat[tid] = 0.f;
}

// ---------------- kernel 2: 32x32-MFMA GEMM + mining; corr head on by<8 ----
// C/D layout (m74/m101): col = lane&31, row = (reg&3) + 8*(reg>>2) + 4*(lane>>5).
// A: row = lane&31, k = ki*16 + (lane>>5)*8 + [0,8). B: col = lane&31, same k.
template<bool DIAG>
__device__ __forceinline__ void tile_body(const __hip_bfloat16* __restrict__ sB,
                                          const float* __restrict__ sX2,
                                          const bf16x8 (&a)[8],
                                          const float (&x2ih)[16],
                                          float (&nl)[16], float (&ns)[16],
                                          int col, int hi, int d0) {
    const __hip_bfloat16* bp = sB + col * LDS_STRIDE + hi * 8;  // col includes jt*32
    const float xjh = sX2[col];                                 // -0.5*x2j
    f32x16 acc;
#pragma unroll
    for (int r = 0; r < 16; ++r) acc[r] = x2ih[r] + xjh;
#pragma unroll
    for (int ki = 0; ki < 8; ++ki) {
        bf16x8 b = *(const bf16x8*)(bp + ki * 16);
        acc = __builtin_amdgcn_mfma_f32_32x32x16_bf16(a[ki], b, acc, 0, 0, 0);
    }
#pragma unroll
    for (int r = 0; r < 16; ++r) {
        const int R = (r & 3) + 8 * (r >> 2);        // compile-time row offset
        float d2h = fmaxf(-acc[r], EPS_T);           // = AK1^2*d2/2, clipped
        float t = __builtin_amdgcn_sqrtf(d2h);       // dist = t*ln2
        float ne = __builtin_amdgcn_exp2f(-t);       // exp(-dist)
        if (DIAG) ne = (d0 == R) ? 0.f : ne;         // self-pair
        nl[r] += ne;
        ns[r] = fmaf(ne, t, ns[r]);
    }
}

__global__ __launch_bounds__(256, 2) void pairs_kernel(
        const __hip_bfloat16* __restrict__ Fb,
        const float* __restrict__ x2,
        const float* __restrict__ F,
        const int* __restrict__ labels,
        float2* __restrict__ partial,
        float4* __restrict__ corr,
        int jspan) {
    __shared__ __hip_bfloat16 sB[JTILE * LDS_STRIDE];
    __shared__ float sX2[JTILE];     // -0.5 * x2j (t-units)
    __shared__ int sIdx[GCAP];
    __shared__ int sCnt;

    const int tid = threadIdx.x;
    const int bx = blockIdx.x, by = blockIdx.y;

    // ---- corr head: 512 blocks (by<8), one label each, before the j-loop --
    if (by < 8) {
        const int L = by * 64 + bx;
        if (tid == 0) sCnt = 0;
        __syncthreads();
        for (int it = 0; it < NROWS / 1024; ++it) {     // 8 iterations
            const int g = it * 1024 + tid * 4;
            int4 lv = *(const int4*)(labels + g);
#pragma unroll
            for (int k = 0; k < 4; ++k) {
                int lab = (k == 0) ? lv.x : (k == 1) ? lv.y : (k == 2) ? lv.z : lv.w;
                if (lab == L) {
                    int pos = atomicAdd(&sCnt, 1);
                    if (pos < GCAP) sIdx[pos] = g + k;
                }
            }
        }
        __syncthreads();
        const int gsz = sCnt < GCAP ? sCnt : GCAP;
        if (gsz > 0) {
            float* sAcc = (float*)sB;          // overlay, pre-staging
            float* plA = sAcc;
            float* psA = sAcc + GCAP;
            float* nlA = sAcc + 2 * GCAP;
            float* nsA = sAcc + 3 * GCAP;
            if (tid < GCAP) { plA[tid] = 0.f; psA[tid] = 0.f; nlA[tid] = 0.f; nsA[tid] = 0.f; }
            __syncthreads();
            const int npair = gsz * gsz;
            for (int p = tid; p < npair; p += 256) {
                const int aI = p / gsz, bI = p - aI * gsz;
                if (aI == bI) continue;
                const float4* pa = (const float4*)(F + (size_t)sIdx[aI] * DIM);
                const float4* pb = (const float4*)(F + (size_t)sIdx[bI] * DIM);
                float dot = 0.f, ssa = 0.f, ssb = 0.f;
#pragma unroll 8
                for (int u = 0; u < 32; ++u) {
                    float4 va = pa[u], vb = pb[u];
                    dot = fmaf(va.x, vb.x, fmaf(va.y, vb.y, fmaf(va.z, vb.z, fmaf(va.w, vb.w, dot))));
                    ssa = fmaf(va.x, va.x, fmaf(va.y, va.y, fmaf(va.z, va.z, fmaf(va.w, va.w, ssa))));
                    ssb = fmaf(vb.x, vb.x, fmaf(vb.y, vb.y, fmaf(vb.z, vb.z, fmaf(vb.w, vb.w, ssb))));
                }
                float d2h = fmaxf((0.5f * (ssa + ssb) - dot) * AK1SQ, EPS_T);
                float t = __builtin_amdgcn_sqrtf(d2h);
                float ne = __builtin_amdgcn_exp2f(-t);
                float pe = __builtin_amdgcn_exp2f(t + C2F);
                unsafeAtomicAdd(&nlA[aI], ne);
                unsafeAtomicAdd(&nsA[aI], ne * t);
                unsafeAtomicAdd(&plA[aI], pe);
                unsafeAtomicAdd(&psA[aI], pe * t);
            }
            __syncthreads();
            if (tid < gsz)
                corr[sIdx[tid]] = make_float4(plA[tid], psA[tid], -nlA[tid], -nsA[tid]);
        }
        __syncthreads();   // corr LDS use done before staging overwrites
    }

    // ---- main loop: 128 i-rows per block, 32 per wave (one 32-row group) --
    const int wave = tid >> 6;
    const int lane = tid & 63;
    const int col = lane & 31;     // A-row / B-col / C-col index
    const int hi = lane >> 5;      // k-half selector
    const int ibw = bx * 128 + wave * 32;

    bf16x8 a[8];
#pragma unroll
    for (int ki = 0; ki < 8; ++ki)
        a[ki] = *(const bf16x8*)(Fb + (size_t)(ibw + col) * DIM + ki * 16 + hi * 8);

    float x2ih[16];
#pragma unroll
    for (int r = 0; r < 16; ++r)
        x2ih[r] = -0.5f * x2[ibw + ((r & 3) + 8 * (r >> 2)) + 4 * hi];

    float nl[16], ns[16];
#pragma unroll
    for (int r = 0; r < 16; ++r) { nl[r] = 0.f; ns[r] = 0.f; }

    const int jiters = jspan >> 6;
    const int j0 = by * jspan;
    // block's 128 i-rows span global 64-j tiles 2*bx and 2*bx+1
    const int djb0 = 2 * bx - by * jiters;

    for (int jb = 0; jb < jiters; ++jb) {
        const int jbase = j0 + jb * JTILE;
        __syncthreads();   // previous tile's readers done
#pragma unroll
        for (int s = 0; s < 4; ++s) {
            int c = tid + s * 256;
            int jr = c >> 4, ck = c & 15;
            *(bf16x8*)(sB + jr * LDS_STRIDE + ck * 8) =
                *(const bf16x8*)(Fb + (size_t)(jbase + jr) * DIM + ck * 8);
        }
        if (tid < JTILE) sX2[tid] = -0.5f * x2[jbase + tid];
        __syncthreads();

        const bool diag = (unsigned)(jb - djb0) <= 1u;
#pragma unroll
        for (int jt = 0; jt < 2; ++jt) {
            const int jcol = jt * 32 + col;
            const int d0 = jbase + jcol - ibw - 4 * hi;   // self iff == R
            if (diag)
                tile_body<true >(sB, sX2, a, x2ih, nl, ns, jcol, hi, d0);
            else
                tile_body<false>(sB, sX2, a, x2ih, nl, ns, jcol, hi, d0);
        }
    }

    // row-sums: reduce over the 32 cols (lanes within each half-wave)
#pragma unroll
    for (int m = 1; m < 32; m <<= 1) {
#pragma unroll
        for (int r = 0; r < 16; ++r) {
            nl[r] += __shfl_xor(nl[r], m, 64);
            ns[r] += __shfl_xor(ns[r], m, 64);
        }
    }
    if (col == 0) {      // lanes 0 and 32 each write their 16 rows
#pragma unroll
        for (int r = 0; r < 16; ++r)
            partial[(size_t)by * NROWS + ibw + ((r & 3) + 8 * (r >> 2)) + 4 * hi] =
                make_float2(nl[r], ns[r]);
    }
}

// ---------------- kernel 3: per-row loss, reduce, final divide -------------
__global__ __launch_bounds__(256) void finalize_kernel(const float2* __restrict__ partial,
                                                       const float4* __restrict__ corr,
                                                       float* __restrict__ gstat,
                                                       float* __restrict__ out,
                                                       int jsplit) {
    const int row = blockIdx.x * 256 + threadIdx.x;
    float4 c = corr[row];
    float nl = c.z, ns = c.w;    // negative corrections (subtract same-label mass)
    for (int s = 0; s < jsplit; ++s) {
        float2 p = partial[(size_t)s * NROWS + row];
        nl += p.x; ns += p.y;
    }
    float sum = 0.f, cnt = 0.f;
    if (c.x > 0.f && nl > 0.f) {
        float x = fmaf(LN2F, c.y / c.x - ns / nl, MARGIN_F);   // wp - wn + margin
        sum = fmaxf(x, 0.f) + log1pf(__expf(-fabsf(x)));       // stable softplus
        cnt = 1.f;
    }
#pragma unroll
    for (int m = 32; m > 0; m >>= 1) {
        sum += __shfl_xor(sum, m, 64);
        cnt += __shfl_xor(cnt, m, 64);
    }
    __shared__ float sS[4], sC[4];
    const int wave = threadIdx.x >> 6, lane = threadIdx.x & 63;
    if (lane == 0) { sS[wave] = sum; sC[wave] = cnt; }
    __syncthreads();
    if (threadIdx.x == 0) {
        unsafeAtomicAdd(&gstat[0], sS[0] + sS[1] + sS[2] + sS[3]);
        unsafeAtomicAdd(&gstat[1], sC[0] + sC[1] + sC[2] + sC[3]);
        __threadfence();
        unsigned t = atomicAdd((unsigned*)(gstat + 2), 1u);
        if (t == (unsigned)(gridDim.x - 1)) {
            float s2 = unsafeAtomicAdd(&gstat[0], 0.f);   // L2 reads
            float c2 = unsafeAtomicAdd(&gstat[1], 0.f);
            out[0] = s2 / fmaxf(c2, 1.f);
        }
    }
}

extern "C" void kernel_launch(void* const* d_in, const int* in_sizes, int n_in,
                              void* d_out, int out_size, void* d_ws, size_t ws_size,
                              hipStream_t stream) {
    const float* F = (const float*)d_in[0];
    const int* labels = (const int*)d_in[1];
    float* out = (float*)d_out;

    char* ws = (char*)d_ws;
    __hip_bfloat16* Fb = (__hip_bfloat16*)ws;                        // 2 MB
    size_t off = (size_t)NROWS * DIM * 2;
    float* x2 = (float*)(ws + off);    off += (size_t)NROWS * 4;     // 32 KB
    float4* corr = (float4*)(ws + off); off += (size_t)NROWS * 16;   // 128 KB

    int jsplit = 32;
    while (jsplit > 8 && off + (size_t)jsplit * NROWS * 8 + 16 > ws_size) jsplit >>= 1;
    float2* partial = (float2*)(ws + off);
    off += (size_t)jsplit * NROWS * 8;
    float* gstat = (float*)(ws + off);                               // 16 B

    prep_kernel<<<NROWS / 4, 256, 0, stream>>>(F, Fb, x2, gstat);
    pairs_kernel<<<dim3(NROWS / 128, jsplit), 256, 0, stream>>>(
        Fb, x2, F, labels, partial, corr, NROWS / jsplit);
    finalize_kernel<<<NROWS / 256, 256, 0, stream>>>(partial, corr, gstat, out, jsplit);
}

// Round 15
// 111.647 us; speedup vs baseline: 1.1281x; 1.1281x over previous
//
#include <hip/hip_runtime.h>
#include <hip/hip_bf16.h>

// TripletLoss N=8192, D=128. Round 16: round-8 base + pipelined staging.
// Round-15 post-mortem: 32x32 at 2x blocks -> occupancy 21->25%, dur flat
// (61us) -- block-supply theory falsified; 16x16 round-8 (49.5us) stays the
// best base. All pipes <40% busy vs ~13us ideal compute => the 2-barrier
// {barrier; stage; barrier+vmcnt0; compute} tile loop exposes the full
// staging latency (guide m233: that structure's stall = 72% of critical
// path). ONE change: double-buffered LDS + T14 issue-early/write-late --
// per tile: issue next tile's global loads to 16 regs BEFORE compute,
// compute buf[cur], ds_write regs to buf[cur^1], ONE barrier per tile.
// (256,3) raises the arch-reg cap to ~85 for the +16 staged regs.
// t-units: Fb,x2 pre-scaled by AK1=sqrt2*log2(e); C-init -(x2i+x2j)/2 =>
// acc = -AK1^2*d2/2; t=sqrt(-acc); exp(-dist)=exp2(-t); dist=t*ln2;
// positives exp(dist-30)=exp2(t+C2).

typedef __bf16 bf16x8 __attribute__((ext_vector_type(8)));
typedef float f32x4 __attribute__((ext_vector_type(4)));

#define NROWS 8192
#define DIM 128
#define JTILE 64
#define LDS_STRIDE 136    // 128+8 bf16 pad: 272B rows (17x16B, odd -> b128 spread)
#define NLABELS 512
#define GCAP 64           // max rows/label (E=16; P(>64) ~ 1e-30)
#define JSPLIT 16
#define JSPAN (NROWS / JSPLIT)   // 512
#define JITERS (JSPAN / JTILE)   // 8
#define MARGIN_F 0.3f
#define AK1F 2.04027892f      // sqrt2 * log2(e)
#define AK1SQ 4.16273807f     // AK1^2
#define EPS_T 2.08137e-8f     // AK1^2 * 5e-9 (matches reference clip(d2,1e-8))
#define C2F (-43.2808512f)    // -30*log2(e)
#define LN2F 0.69314718f

// ---------------- kernel 1: scaled bf16 cast + row norms + zero gstat ------
__global__ __launch_bounds__(256) void prep_kernel(const float* __restrict__ F,
                                                   __hip_bfloat16* __restrict__ Fb,
                                                   float* __restrict__ x2,
                                                   float* __restrict__ gstat) {
    const int tid = threadIdx.x;
    const int wave = tid >> 6, lane = tid & 63;
    const int row = blockIdx.x * 4 + wave;
    float2 f = ((const float2*)(F + (size_t)row * DIM))[lane];
    f.x *= AK1F; f.y *= AK1F;
    ((__hip_bfloat162*)(Fb + (size_t)row * DIM))[lane] = __float22bfloat162_rn(f);
    float ss = f.x * f.x + f.y * f.y;
#pragma unroll
    for (int m = 32; m > 0; m >>= 1) ss += __shfl_xor(ss, m, 64);
    if (lane == 0) x2[row] = ss;
    if (blockIdx.x == 0 && tid < 4) gstat[tid] = 0.f;
}

// ---------------- kernel 2: fused GEMM + mining; corr head on by<4 ---------
// 64 i-rows per block: 16 per wave (16x16 MFMA, proven spill-free reg set).
template<bool DIAG>
__device__ __forceinline__ void tile_body(const __hip_bfloat16* __restrict__ sB,
                                          const float* __restrict__ sX2h,
                                          const bf16x8 (&a)[4],
                                          const float (&x2ih)[4],
                                          float (&nl4)[4], float (&ns4)[4],
                                          int lm, int quad, int ig0, int jbase) {
#pragma unroll
    for (int jt = 0; jt < 4; ++jt) {
        const int jl = jt * 16 + lm;
        const __hip_bfloat16* bp = sB + jl * LDS_STRIDE + quad * 8;
        const float xjh = sX2h[jl];
        f32x4 acc;
#pragma unroll
        for (int r = 0; r < 4; ++r) acc[r] = x2ih[r] + xjh;
#pragma unroll
        for (int kc = 0; kc < 4; ++kc) {
            bf16x8 b = *(const bf16x8*)(bp + kc * 32);
            acc = __builtin_amdgcn_mfma_f32_16x16x32_bf16(a[kc], b, acc, 0, 0, 0);
        }
        const int dj = jbase + jl - ig0;   // self-pair iff dj == r
#pragma unroll
        for (int r = 0; r < 4; ++r) {
            float d2h = fmaxf(-acc[r], EPS_T);          // = AK1^2*d2/2, clipped
            float t = __builtin_amdgcn_sqrtf(d2h);      // dist = t*ln2
            float ne = __builtin_amdgcn_exp2f(-t);      // exp(-dist)
            if (DIAG) ne = (dj == r) ? 0.f : ne;
            nl4[r] += ne;
            ns4[r] = fmaf(ne, t, ns4[r]);
        }
    }
}

__global__ __launch_bounds__(256, 3) void pairs_kernel(
        const __hip_bfloat16* __restrict__ Fb,
        const float* __restrict__ x2,
        const float* __restrict__ F,
        const int* __restrict__ labels,
        float2* __restrict__ partial,
        float4* __restrict__ corr) {
    __shared__ __hip_bfloat16 sB[2][JTILE * LDS_STRIDE];   // 34 KB double buffer
    __shared__ float sX2[2][JTILE];                        // -0.5 * x2j
    __shared__ int sIdx[GCAP];
    __shared__ int sCnt;

    const int tid = threadIdx.x;
    const int bx = blockIdx.x, by = blockIdx.y;

    // ---- corr head: 512 blocks (by<4), one label each, before the j-loop --
    if (by < 4) {
        const int L = by * 128 + bx;
        if (tid == 0) sCnt = 0;
        __syncthreads();
        for (int it = 0; it < NROWS / 1024; ++it) {     // 8 iterations
            const int g = it * 1024 + tid * 4;
            int4 lv = *(const int4*)(labels + g);
#pragma unroll
            for (int k = 0; k < 4; ++k) {
                int lab = (k == 0) ? lv.x : (k == 1) ? lv.y : (k == 2) ? lv.z : lv.w;
                if (lab == L) {
                    int pos = atomicAdd(&sCnt, 1);
                    if (pos < GCAP) sIdx[pos] = g + k;
                }
            }
        }
        __syncthreads();
        const int gsz = sCnt < GCAP ? sCnt : GCAP;
        if (gsz > 0) {
            float* sAcc = (float*)sB;          // overlay, pre-staging
            float* plA = sAcc;
            float* psA = sAcc + GCAP;
            float* nlA = sAcc + 2 * GCAP;
            float* nsA = sAcc + 3 * GCAP;
            if (tid < GCAP) { plA[tid] = 0.f; psA[tid] = 0.f; nlA[tid] = 0.f; nsA[tid] = 0.f; }
            __syncthreads();
            const int npair = gsz * gsz;
            for (int p = tid; p < npair; p += 256) {
                const int aI = p / gsz, bI = p - aI * gsz;
                if (aI == bI) continue;
                const float4* pa = (const float4*)(F + (size_t)sIdx[aI] * DIM);
                const float4* pb = (const float4*)(F + (size_t)sIdx[bI] * DIM);
                float dot = 0.f, ssa = 0.f, ssb = 0.f;
#pragma unroll 8
                for (int u = 0; u < 32; ++u) {
                    float4 va = pa[u], vb = pb[u];
                    dot = fmaf(va.x, vb.x, fmaf(va.y, vb.y, fmaf(va.z, vb.z, fmaf(va.w, vb.w, dot))));
                    ssa = fmaf(va.x, va.x, fmaf(va.y, va.y, fmaf(va.z, va.z, fmaf(va.w, va.w, ssa))));
                    ssb = fmaf(vb.x, vb.x, fmaf(vb.y, vb.y, fmaf(vb.z, vb.z, fmaf(vb.w, vb.w, ssb))));
                }
                float d2h = fmaxf((0.5f * (ssa + ssb) - dot) * AK1SQ, EPS_T);
                float t = __builtin_amdgcn_sqrtf(d2h);
                float ne = __builtin_amdgcn_exp2f(-t);
                float pe = __builtin_amdgcn_exp2f(t + C2F);
                unsafeAtomicAdd(&nlA[aI], ne);
                unsafeAtomicAdd(&nsA[aI], ne * t);
                unsafeAtomicAdd(&plA[aI], pe);
                unsafeAtomicAdd(&psA[aI], pe * t);
            }
            __syncthreads();
            if (tid < gsz)
                corr[sIdx[tid]] = make_float4(plA[tid], psA[tid], -nlA[tid], -nsA[tid]);
        }
        __syncthreads();   // corr LDS use done before staging overwrites
    }

    // ---- A-fragments + x2i (round-8 mapping) ----
    const int wave = tid >> 6;
    const int lane = tid & 63;
    const int quad = lane >> 4;
    const int lm = lane & 15;
    const int rbase = bx * 64 + wave * 16;

    bf16x8 a[4];
#pragma unroll
    for (int kc = 0; kc < 4; ++kc)
        a[kc] = *(const bf16x8*)(Fb + (size_t)(rbase + lm) * DIM + kc * 32 + quad * 8);

    const int ig0 = rbase + quad * 4;
    float x2ih[4];
#pragma unroll
    for (int r = 0; r < 4; ++r) x2ih[r] = -0.5f * x2[ig0 + r];

    float nl4[4] = {0,0,0,0}, ns4[4] = {0,0,0,0};

    const int j0 = by * JSPAN;
    const int djb = bx - by * JITERS;   // jb holding the diagonal (if in range)

    // ---- pipelined j-loop: issue-early / write-late, 1 barrier per tile ---
    const int c0 = tid, c1 = tid + 256, c2 = tid + 512, c3 = tid + 768;
    uint4 st0, st1, st2, st3;
    float xv;
#define LOADTILE(JB) do {                                                      \
        const size_t jo = (size_t)(JB);                                        \
        st0 = *(const uint4*)(Fb + (jo + (c0 >> 4)) * DIM + (c0 & 15) * 8);    \
        st1 = *(const uint4*)(Fb + (jo + (c1 >> 4)) * DIM + (c1 & 15) * 8);    \
        st2 = *(const uint4*)(Fb + (jo + (c2 >> 4)) * DIM + (c2 & 15) * 8);    \
        st3 = *(const uint4*)(Fb + (jo + (c3 >> 4)) * DIM + (c3 & 15) * 8);    \
        if (tid < JTILE) xv = x2[jo + tid];                                    \
    } while (0)
#define WRITETILE(B) do {                                                      \
        __hip_bfloat16* sb = sB[B];                                            \
        *(uint4*)(sb + (c0 >> 4) * LDS_STRIDE + (c0 & 15) * 8) = st0;          \
        *(uint4*)(sb + (c1 >> 4) * LDS_STRIDE + (c1 & 15) * 8) = st1;          \
        *(uint4*)(sb + (c2 >> 4) * LDS_STRIDE + (c2 & 15) * 8) = st2;          \
        *(uint4*)(sb + (c3 >> 4) * LDS_STRIDE + (c3 & 15) * 8) = st3;          \
        if (tid < JTILE) sX2[B][tid] = -0.5f * xv;                             \
    } while (0)

    LOADTILE(j0);          // prologue: tile 0
    WRITETILE(0);
    __syncthreads();
    int cur = 0;
    for (int jb = 0; jb < JITERS; ++jb) {
        if (jb + 1 < JITERS) LOADTILE(j0 + (jb + 1) * JTILE);  // in flight
        const int jbase = j0 + jb * JTILE;                     // during compute
        if (jb == djb)
            tile_body<true >(sB[cur], sX2[cur], a, x2ih, nl4, ns4, lm, quad, ig0, jbase);
        else
            tile_body<false>(sB[cur], sX2[cur], a, x2ih, nl4, ns4, lm, quad, ig0, jbase);
        if (jb + 1 < JITERS) WRITETILE(cur ^ 1);   // other buffer: no race
        __syncthreads();   // writes visible; all waves done reading buf[cur]
        cur ^= 1;
    }
#undef LOADTILE
#undef WRITETILE

    // reduce over the 16 lanes (lm) sharing each i-row
#pragma unroll
    for (int m = 1; m < 16; m <<= 1) {
#pragma unroll
        for (int r = 0; r < 4; ++r) {
            nl4[r] += __shfl_xor(nl4[r], m, 64);
            ns4[r] += __shfl_xor(ns4[r], m, 64);
        }
    }
    if (lm == 0) {
#pragma unroll
        for (int r = 0; r < 4; ++r)
            partial[(size_t)by * NROWS + ig0 + r] = make_float2(nl4[r], ns4[r]);
    }
}

// ---------------- kernel 3: per-row loss, reduce, final divide -------------
__global__ __launch_bounds__(256) void finalize_kernel(const float2* __restrict__ partial,
                                                       const float4* __restrict__ corr,
                                                       float* __restrict__ gstat,
                                                       float* __restrict__ out) {
    const int row = blockIdx.x * 256 + threadIdx.x;
    float4 c = corr[row];
    float nl = c.z, ns = c.w;    // negative corrections (subtract same-label mass)
#pragma unroll
    for (int s = 0; s < JSPLIT; ++s) {
        float2 p = partial[(size_t)s * NROWS + row];
        nl += p.x; ns += p.y;
    }
    float sum = 0.f, cnt = 0.f;
    if (c.x > 0.f && nl > 0.f) {
        float x = fmaf(LN2F, c.y / c.x - ns / nl, MARGIN_F);   // wp - wn + margin
        sum = fmaxf(x, 0.f) + log1pf(__expf(-fabsf(x)));       // stable softplus
        cnt = 1.f;
    }
#pragma unroll
    for (int m = 32; m > 0; m >>= 1) {
        sum += __shfl_xor(sum, m, 64);
        cnt += __shfl_xor(cnt, m, 64);
    }
    __shared__ float sS[4], sC[4];
    const int wave = threadIdx.x >> 6, lane = threadIdx.x & 63;
    if (lane == 0) { sS[wave] = sum; sC[wave] = cnt; }
    __syncthreads();
    if (threadIdx.x == 0) {
        unsafeAtomicAdd(&gstat[0], sS[0] + sS[1] + sS[2] + sS[3]);
        unsafeAtomicAdd(&gstat[1], sC[0] + sC[1] + sC[2] + sC[3]);
        __threadfence();
        unsigned t = atomicAdd((unsigned*)(gstat + 2), 1u);
        if (t == (unsigned)(gridDim.x - 1)) {
            float s2 = unsafeAtomicAdd(&gstat[0], 0.f);   // L2 reads
            float c2 = unsafeAtomicAdd(&gstat[1], 0.f);
            out[0] = s2 / fmaxf(c2, 1.f);
        }
    }
}

extern "C" void kernel_launch(void* const* d_in, const int* in_sizes, int n_in,
                              void* d_out, int out_size, void* d_ws, size_t ws_size,
                              hipStream_t stream) {
    const float* F = (const float*)d_in[0];
    const int* labels = (const int*)d_in[1];
    float* out = (float*)d_out;

    char* ws = (char*)d_ws;
    __hip_bfloat16* Fb = (__hip_bfloat16*)ws;                        // 2 MB
    size_t off = (size_t)NROWS * DIM * 2;
    float* x2 = (float*)(ws + off);    off += (size_t)NROWS * 4;     // 32 KB
    float4* corr = (float4*)(ws + off); off += (size_t)NROWS * 16;   // 128 KB
    float2* partial = (float2*)(ws + off);                           // 1 MB
    off += (size_t)JSPLIT * NROWS * 8;
    float* gstat = (float*)(ws + off);                               // 16 B

    prep_kernel<<<NROWS / 4, 256, 0, stream>>>(F, Fb, x2, gstat);
    pairs_kernel<<<dim3(NROWS / 64, JSPLIT), 256, 0, stream>>>(
        Fb, x2, F, labels, partial, corr);
    finalize_kernel<<<NROWS / 256, 256, 0, stream>>>(partial, corr, gstat, out);
}

// Round 16
// 109.666 us; speedup vs baseline: 1.1485x; 1.0181x over previous
//
#include <hip/hip_runtime.h>
#include <hip/hip_bf16.h>

// TripletLoss N=8192, D=128. Round 17: pipelined staging at r8's LDS budget.
// Round-16 post-mortem: 1-barrier pipeline worked but doubling LDS (17.9 ->
// 35.8KB) cut occupancy 37->25% -- net LOSS (58.4 vs r8's 49.5). This round
// keeps the validated pipelined loop and halves the tile: JTILE 64 -> 32
// double-buffered = 17.4KB total (r8's footprint), staged regs 16 -> 8.
// Per tile: issue next tile's 2 global loads -> compute (8 MFMA + epilogue,
// ~300cy covers L2 latency) -> ds_write other buffer -> ONE barrier (LDS
// wait only, no vmcnt(0) global drain).
// t-units: Fb,x2 pre-scaled by AK1=sqrt2*log2(e); C-init -(x2i+x2j)/2 =>
// acc = -AK1^2*d2/2; t=sqrt(-acc); exp(-dist)=exp2(-t); dist=t*ln2;
// positives exp(dist-30)=exp2(t+C2).

typedef __bf16 bf16x8 __attribute__((ext_vector_type(8)));
typedef float f32x4 __attribute__((ext_vector_type(4)));

#define NROWS 8192
#define DIM 128
#define JTILE 32
#define LDS_STRIDE 136    // 128+8 bf16 pad: 272B rows (17x16B, odd -> b128 spread)
#define NLABELS 512
#define GCAP 64           // max rows/label (E=16; P(>64) ~ 1e-30)
#define JSPLIT 16
#define JSPAN (NROWS / JSPLIT)   // 512
#define JITERS (JSPAN / JTILE)   // 16
#define MARGIN_F 0.3f
#define AK1F 2.04027892f      // sqrt2 * log2(e)
#define AK1SQ 4.16273807f     // AK1^2
#define EPS_T 2.08137e-8f     // AK1^2 * 5e-9 (matches reference clip(d2,1e-8))
#define C2F (-43.2808512f)    // -30*log2(e)
#define LN2F 0.69314718f

// ---------------- kernel 1: scaled bf16 cast + row norms + zero gstat ------
__global__ __launch_bounds__(256) void prep_kernel(const float* __restrict__ F,
                                                   __hip_bfloat16* __restrict__ Fb,
                                                   float* __restrict__ x2,
                                                   float* __restrict__ gstat) {
    const int tid = threadIdx.x;
    const int wave = tid >> 6, lane = tid & 63;
    const int row = blockIdx.x * 4 + wave;
    float2 f = ((const float2*)(F + (size_t)row * DIM))[lane];
    f.x *= AK1F; f.y *= AK1F;
    ((__hip_bfloat162*)(Fb + (size_t)row * DIM))[lane] = __float22bfloat162_rn(f);
    float ss = f.x * f.x + f.y * f.y;
#pragma unroll
    for (int m = 32; m > 0; m >>= 1) ss += __shfl_xor(ss, m, 64);
    if (lane == 0) x2[row] = ss;
    if (blockIdx.x == 0 && tid < 4) gstat[tid] = 0.f;
}

// ---------------- kernel 2: fused GEMM + mining; corr head on by<4 ---------
// 64 i-rows per block, 16 per wave (16x16 MFMA); 32-col j-tiles (2 jt groups).
template<bool DIAG>
__device__ __forceinline__ void tile_body(const __hip_bfloat16* __restrict__ sB,
                                          const float* __restrict__ sX2h,
                                          const bf16x8 (&a)[4],
                                          const float (&x2ih)[4],
                                          float (&nl4)[4], float (&ns4)[4],
                                          int lm, int quad, int ig0, int jbase) {
#pragma unroll
    for (int jt = 0; jt < 2; ++jt) {
        const int jl = jt * 16 + lm;
        const __hip_bfloat16* bp = sB + jl * LDS_STRIDE + quad * 8;
        const float xjh = sX2h[jl];
        f32x4 acc;
#pragma unroll
        for (int r = 0; r < 4; ++r) acc[r] = x2ih[r] + xjh;
#pragma unroll
        for (int kc = 0; kc < 4; ++kc) {
            bf16x8 b = *(const bf16x8*)(bp + kc * 32);
            acc = __builtin_amdgcn_mfma_f32_16x16x32_bf16(a[kc], b, acc, 0, 0, 0);
        }
        const int dj = jbase + jl - ig0;   // self-pair iff dj == r
#pragma unroll
        for (int r = 0; r < 4; ++r) {
            float d2h = fmaxf(-acc[r], EPS_T);          // = AK1^2*d2/2, clipped
            float t = __builtin_amdgcn_sqrtf(d2h);      // dist = t*ln2
            float ne = __builtin_amdgcn_exp2f(-t);      // exp(-dist)
            if (DIAG) ne = (dj == r) ? 0.f : ne;
            nl4[r] += ne;
            ns4[r] = fmaf(ne, t, ns4[r]);
        }
    }
}

__global__ __launch_bounds__(256, 3) void pairs_kernel(
        const __hip_bfloat16* __restrict__ Fb,
        const float* __restrict__ x2,
        const float* __restrict__ F,
        const int* __restrict__ labels,
        float2* __restrict__ partial,
        float4* __restrict__ corr) {
    __shared__ __hip_bfloat16 sB[2][JTILE * LDS_STRIDE];   // 17.4 KB double buffer
    __shared__ float sX2[2][JTILE];                        // -0.5 * x2j
    __shared__ int sIdx[GCAP];
    __shared__ int sCnt;

    const int tid = threadIdx.x;
    const int bx = blockIdx.x, by = blockIdx.y;

    // ---- corr head: 512 blocks (by<4), one label each, before the j-loop --
    if (by < 4) {
        const int L = by * 128 + bx;
        if (tid == 0) sCnt = 0;
        __syncthreads();
        for (int it = 0; it < NROWS / 1024; ++it) {     // 8 iterations
            const int g = it * 1024 + tid * 4;
            int4 lv = *(const int4*)(labels + g);
#pragma unroll
            for (int k = 0; k < 4; ++k) {
                int lab = (k == 0) ? lv.x : (k == 1) ? lv.y : (k == 2) ? lv.z : lv.w;
                if (lab == L) {
                    int pos = atomicAdd(&sCnt, 1);
                    if (pos < GCAP) sIdx[pos] = g + k;
                }
            }
        }
        __syncthreads();
        const int gsz = sCnt < GCAP ? sCnt : GCAP;
        if (gsz > 0) {
            float* sAcc = (float*)sB;          // overlay, pre-staging
            float* plA = sAcc;
            float* psA = sAcc + GCAP;
            float* nlA = sAcc + 2 * GCAP;
            float* nsA = sAcc + 3 * GCAP;
            if (tid < GCAP) { plA[tid] = 0.f; psA[tid] = 0.f; nlA[tid] = 0.f; nsA[tid] = 0.f; }
            __syncthreads();
            const int npair = gsz * gsz;
            for (int p = tid; p < npair; p += 256) {
                const int aI = p / gsz, bI = p - aI * gsz;
                if (aI == bI) continue;
                const float4* pa = (const float4*)(F + (size_t)sIdx[aI] * DIM);
                const float4* pb = (const float4*)(F + (size_t)sIdx[bI] * DIM);
                float dot = 0.f, ssa = 0.f, ssb = 0.f;
#pragma unroll 8
                for (int u = 0; u < 32; ++u) {
                    float4 va = pa[u], vb = pb[u];
                    dot = fmaf(va.x, vb.x, fmaf(va.y, vb.y, fmaf(va.z, vb.z, fmaf(va.w, vb.w, dot))));
                    ssa = fmaf(va.x, va.x, fmaf(va.y, va.y, fmaf(va.z, va.z, fmaf(va.w, va.w, ssa))));
                    ssb = fmaf(vb.x, vb.x, fmaf(vb.y, vb.y, fmaf(vb.z, vb.z, fmaf(vb.w, vb.w, ssb))));
                }
                float d2h = fmaxf((0.5f * (ssa + ssb) - dot) * AK1SQ, EPS_T);
                float t = __builtin_amdgcn_sqrtf(d2h);
                float ne = __builtin_amdgcn_exp2f(-t);
                float pe = __builtin_amdgcn_exp2f(t + C2F);
                unsafeAtomicAdd(&nlA[aI], ne);
                unsafeAtomicAdd(&nsA[aI], ne * t);
                unsafeAtomicAdd(&plA[aI], pe);
                unsafeAtomicAdd(&psA[aI], pe * t);
            }
            __syncthreads();
            if (tid < gsz)
                corr[sIdx[tid]] = make_float4(plA[tid], psA[tid], -nlA[tid], -nsA[tid]);
        }
        __syncthreads();   // corr LDS use done before staging overwrites
    }

    // ---- A-fragments + x2i (r8 mapping) ----
    const int wave = tid >> 6;
    const int lane = tid & 63;
    const int quad = lane >> 4;
    const int lm = lane & 15;
    const int rbase = bx * 64 + wave * 16;

    bf16x8 a[4];
#pragma unroll
    for (int kc = 0; kc < 4; ++kc)
        a[kc] = *(const bf16x8*)(Fb + (size_t)(rbase + lm) * DIM + kc * 32 + quad * 8);

    const int ig0 = rbase + quad * 4;
    float x2ih[4];
#pragma unroll
    for (int r = 0; r < 4; ++r) x2ih[r] = -0.5f * x2[ig0 + r];

    float nl4[4] = {0,0,0,0}, ns4[4] = {0,0,0,0};

    const int j0 = by * JSPAN;
    // block's 64 i-rows span two 32-col j-tiles: jb = 2*bx - 16*by and +1
    const int djb0 = 2 * bx - by * JITERS;

    // ---- pipelined j-loop: issue-early / write-late, 1 barrier per tile ---
    const int c0 = tid, c1 = tid + 256;      // 512 chunks = 32 rows x 16
    uint4 st0, st1;
    float xv;
#define LOADTILE(JB) do {                                                      \
        const size_t jo = (size_t)(JB);                                        \
        st0 = *(const uint4*)(Fb + (jo + (c0 >> 4)) * DIM + (c0 & 15) * 8);    \
        st1 = *(const uint4*)(Fb + (jo + (c1 >> 4)) * DIM + (c1 & 15) * 8);    \
        if (tid < JTILE) xv = x2[jo + tid];                                    \
    } while (0)
#define WRITETILE(B) do {                                                      \
        __hip_bfloat16* sb = sB[B];                                            \
        *(uint4*)(sb + (c0 >> 4) * LDS_STRIDE + (c0 & 15) * 8) = st0;          \
        *(uint4*)(sb + (c1 >> 4) * LDS_STRIDE + (c1 & 15) * 8) = st1;          \
        if (tid < JTILE) sX2[B][tid] = -0.5f * xv;                             \
    } while (0)

    LOADTILE(j0);          // prologue: tile 0
    WRITETILE(0);
    __syncthreads();
    int cur = 0;
    for (int jb = 0; jb < JITERS; ++jb) {
        if (jb + 1 < JITERS) LOADTILE(j0 + (jb + 1) * JTILE);  // in flight
        const int jbase = j0 + jb * JTILE;                     // during compute
        if ((unsigned)(jb - djb0) <= 1u)
            tile_body<true >(sB[cur], sX2[cur], a, x2ih, nl4, ns4, lm, quad, ig0, jbase);
        else
            tile_body<false>(sB[cur], sX2[cur], a, x2ih, nl4, ns4, lm, quad, ig0, jbase);
        if (jb + 1 < JITERS) WRITETILE(cur ^ 1);   // other buffer: no race
        __syncthreads();   // writes visible; all waves done reading buf[cur]
        cur ^= 1;
    }
#undef LOADTILE
#undef WRITETILE

    // reduce over the 16 lanes (lm) sharing each i-row
#pragma unroll
    for (int m = 1; m < 16; m <<= 1) {
#pragma unroll
        for (int r = 0; r < 4; ++r) {
            nl4[r] += __shfl_xor(nl4[r], m, 64);
            ns4[r] += __shfl_xor(ns4[r], m, 64);
        }
    }
    if (lm == 0) {
#pragma unroll
        for (int r = 0; r < 4; ++r)
            partial[(size_t)by * NROWS + ig0 + r] = make_float2(nl4[r], ns4[r]);
    }
}

// ---------------- kernel 3: per-row loss, reduce, final divide -------------
__global__ __launch_bounds__(256) void finalize_kernel(const float2* __restrict__ partial,
                                                       const float4* __restrict__ corr,
                                                       float* __restrict__ gstat,
                                                       float* __restrict__ out) {
    const int row = blockIdx.x * 256 + threadIdx.x;
    float4 c = corr[row];
    float nl = c.z, ns = c.w;    // negative corrections (subtract same-label mass)
#pragma unroll
    for (int s = 0; s < JSPLIT; ++s) {
        float2 p = partial[(size_t)s * NROWS + row];
        nl += p.x; ns += p.y;
    }
    float sum = 0.f, cnt = 0.f;
    if (c.x > 0.f && nl > 0.f) {
        float x = fmaf(LN2F, c.y / c.x - ns / nl, MARGIN_F);   // wp - wn + margin
        sum = fmaxf(x, 0.f) + log1pf(__expf(-fabsf(x)));       // stable softplus
        cnt = 1.f;
    }
#pragma unroll
    for (int m = 32; m > 0; m >>= 1) {
        sum += __shfl_xor(sum, m, 64);
        cnt += __shfl_xor(cnt, m, 64);
    }
    __shared__ float sS[4], sC[4];
    const int wave = threadIdx.x >> 6, lane = threadIdx.x & 63;
    if (lane == 0) { sS[wave] = sum; sC[wave] = cnt; }
    __syncthreads();
    if (threadIdx.x == 0) {
        unsafeAtomicAdd(&gstat[0], sS[0] + sS[1] + sS[2] + sS[3]);
        unsafeAtomicAdd(&gstat[1], sC[0] + sC[1] + sC[2] + sC[3]);
        __threadfence();
        unsigned t = atomicAdd((unsigned*)(gstat + 2), 1u);
        if (t == (unsigned)(gridDim.x - 1)) {
            float s2 = unsafeAtomicAdd(&gstat[0], 0.f);   // L2 reads
            float c2 = unsafeAtomicAdd(&gstat[1], 0.f);
            out[0] = s2 / fmaxf(c2, 1.f);
        }
    }
}

extern "C" void kernel_launch(void* const* d_in, const int* in_sizes, int n_in,
                              void* d_out, int out_size, void* d_ws, size_t ws_size,
                              hipStream_t stream) {
    const float* F = (const float*)d_in[0];
    const int* labels = (const int*)d_in[1];
    float* out = (float*)d_out;

    char* ws = (char*)d_ws;
    __hip_bfloat16* Fb = (__hip_bfloat16*)ws;                        // 2 MB
    size_t off = (size_t)NROWS * DIM * 2;
    float* x2 = (float*)(ws + off);    off += (size_t)NROWS * 4;     // 32 KB
    float4* corr = (float4*)(ws + off); off += (size_t)NROWS * 16;   // 128 KB
    float2* partial = (float2*)(ws + off);                           // 1 MB
    off += (size_t)JSPLIT * NROWS * 8;
    float* gstat = (float*)(ws + off);                               // 16 B

    prep_kernel<<<NROWS / 4, 256, 0, stream>>>(F, Fb, x2, gstat);
    pairs_kernel<<<dim3(NROWS / 64, JSPLIT), 256, 0, stream>>>(
        Fb, x2, F, labels, partial, corr);
    finalize_kernel<<<NROWS / 256, 256, 0, stream>>>(partial, corr, gstat, out);
}